// Round 1
// baseline (5882.685 us; speedup 1.0000x reference)
//
#include <hip/hip_runtime.h>
#include <math.h>

#define BB 2
#define NN 2048
#define DD 1024
#define HH 16
#define HD 64
#define MM (BB*NN)          /* 4096 */
#define SCALE 0.125f        /* 1/sqrt(64) */

#define QT 16
#define KT 64
#define NQB (NN/QT)         /* 128 */

// ---------------------------------------------------------------------------
// Complex projection GEMM:  Y = Z @ W^T + b   (complex), output head-major
// grid (MM/64, DD/64, 3), block (16,16). blockIdx.z selects q/k/v.
// ---------------------------------------------------------------------------
__global__ __launch_bounds__(256) void proj_kernel(
    const float* __restrict__ Zr, const float* __restrict__ Zi,
    const float* __restrict__ wqr, const float* __restrict__ wqi,
    const float* __restrict__ bqr, const float* __restrict__ bqi,
    const float* __restrict__ wkr, const float* __restrict__ wki,
    const float* __restrict__ bkr, const float* __restrict__ bki,
    const float* __restrict__ wvr, const float* __restrict__ wvi,
    const float* __restrict__ bvr, const float* __restrict__ bvi,
    float* __restrict__ Qr, float* __restrict__ Qi,
    float* __restrict__ Kr, float* __restrict__ Ki,
    float* __restrict__ Vr, float* __restrict__ Vi)
{
    const float *wr, *wi, *br, *bi;
    float *outr, *outi;
    if (blockIdx.z == 0)      { wr=wqr; wi=wqi; br=bqr; bi=bqi; outr=Qr; outi=Qi; }
    else if (blockIdx.z == 1) { wr=wkr; wi=wki; br=bkr; bi=bki; outr=Kr; outi=Ki; }
    else                      { wr=wvr; wi=wvi; br=bvr; bi=bvi; outr=Vr; outi=Vi; }

    __shared__ float Xr_s[64][17], Xi_s[64][17], Wr_s[64][17], Wi_s[64][17];

    const int tx = threadIdx.x, ty = threadIdx.y;
    const int tid = ty * 16 + tx;
    const int m0 = blockIdx.x * 64, o0 = blockIdx.y * 64;

    float ar[4][4] = {}, ai[4][4] = {};

    for (int k0 = 0; k0 < DD; k0 += 16) {
        __syncthreads();
        for (int l = tid; l < 64 * 16; l += 256) {
            int row = l >> 4, kk = l & 15;
            size_t xi = (size_t)(m0 + row) * DD + k0 + kk;
            size_t wiidx = (size_t)(o0 + row) * DD + k0 + kk;
            Xr_s[row][kk] = Zr[xi];
            Xi_s[row][kk] = Zi[xi];
            Wr_s[row][kk] = wr[wiidx];
            Wi_s[row][kk] = wi[wiidx];
        }
        __syncthreads();
        for (int kk = 0; kk < 16; kk++) {
            float xr[4], xim[4], wre[4], wim[4];
#pragma unroll
            for (int i = 0; i < 4; i++) { xr[i]  = Xr_s[ty*4+i][kk]; xim[i] = Xi_s[ty*4+i][kk]; }
#pragma unroll
            for (int j = 0; j < 4; j++) { wre[j] = Wr_s[tx*4+j][kk]; wim[j] = Wi_s[tx*4+j][kk]; }
#pragma unroll
            for (int i = 0; i < 4; i++)
#pragma unroll
                for (int j = 0; j < 4; j++) {
                    ar[i][j] += xr[i]*wre[j] - xim[i]*wim[j];
                    ai[i][j] += xr[i]*wim[j] + xim[i]*wre[j];
                }
        }
    }

#pragma unroll
    for (int i = 0; i < 4; i++) {
        int m = m0 + ty*4 + i;
        int b = m / NN, n = m % NN;
#pragma unroll
        for (int j = 0; j < 4; j++) {
            int o = o0 + tx*4 + j;
            int h = o >> 6, hd = o & 63;
            size_t idx = (((size_t)(b*HH + h))*NN + n)*HD + hd;
            outr[idx] = ar[i][j] + br[o];
            outi[idx] = ai[i][j] + bi[o];
        }
    }
}

// ---------------------------------------------------------------------------
// Flash-style attention: Re(q k^T) with mask, online softmax, complex PV.
// grid (BB*HH*NQB), block 256 = 16 rows x 16 lanes.
// ---------------------------------------------------------------------------
__global__ __launch_bounds__(256) void attn_kernel(
    const float* __restrict__ Qr, const float* __restrict__ Qi,
    const float* __restrict__ Kr, const float* __restrict__ Ki,
    const float* __restrict__ Vr, const float* __restrict__ Vi,
    const int* __restrict__ mask,
    float* __restrict__ Or, float* __restrict__ Oi)
{
    __shared__ float qs_r[QT][HD], qs_i[QT][HD];
    __shared__ float Ks_r[KT][HD+1], Ks_i[KT][HD+1];
    __shared__ float Vs_r[KT][HD+1], Vs_i[KT][HD+1];
    __shared__ float ps[QT][KT+1];

    const int id = blockIdx.x;
    const int nq = id % NQB;
    const int h  = (id / NQB) % HH;
    const int b  = id / (NQB * HH);
    const int tid = threadIdx.x;
    const int r = tid >> 4, g = tid & 15;
    const int n0 = nq * QT;
    const size_t bhbase = ((size_t)(b*HH + h)) * NN * HD;

    for (int l = tid; l < QT * HD; l += 256) {
        int row = l >> 6, d = l & 63;
        size_t gi = bhbase + (size_t)(n0 + row) * HD + d;
        qs_r[row][d] = Qr[gi];
        qs_i[row][d] = Qi[gi];
    }

    float accr[4] = {0,0,0,0}, acci[4] = {0,0,0,0};
    float m_run = -3.0e38f, l_run = 0.0f;

    for (int t0 = 0; t0 < NN; t0 += KT) {
        __syncthreads();
        for (int l = tid; l < KT * HD; l += 256) {
            int row = l >> 6, d = l & 63;
            size_t gi = bhbase + (size_t)(t0 + row) * HD + d;
            Ks_r[row][d] = Kr[gi];
            Ks_i[row][d] = Ki[gi];
            Vs_r[row][d] = Vr[gi];
            Vs_i[row][d] = Vi[gi];
        }
        __syncthreads();

        float s[4];
#pragma unroll
        for (int jj = 0; jj < 4; jj++) {
            int j = g + 16 * jj;
            float acc = 0.0f;
            for (int d = 0; d < HD; d++)
                acc += qs_r[r][d] * Ks_r[j][d] - qs_i[r][d] * Ks_i[j][d];
            acc *= SCALE;
            if (mask[b * NN + t0 + j] == 0) acc = -1e9f;
            s[jj] = acc;
        }
        float tmax = fmaxf(fmaxf(s[0], s[1]), fmaxf(s[2], s[3]));
#pragma unroll
        for (int off = 1; off < 16; off <<= 1)
            tmax = fmaxf(tmax, __shfl_xor(tmax, off, 64));

        float m_new = fmaxf(m_run, tmax);
        float psum = 0.0f;
#pragma unroll
        for (int jj = 0; jj < 4; jj++) {
            float p = __expf(s[jj] - m_new);
            psum += p;
            ps[r][g + 16 * jj] = p;
        }
#pragma unroll
        for (int off = 1; off < 16; off <<= 1)
            psum += __shfl_xor(psum, off, 64);

        float fac = __expf(m_run - m_new);
        l_run = l_run * fac + psum;
        m_run = m_new;
#pragma unroll
        for (int c = 0; c < 4; c++) { accr[c] *= fac; acci[c] *= fac; }
        __syncthreads();

        for (int j = 0; j < KT; j++) {
            float p = ps[r][j];
#pragma unroll
            for (int c = 0; c < 4; c++) {
                accr[c] += p * Vs_r[j][g*4 + c];
                acci[c] += p * Vs_i[j][g*4 + c];
            }
        }
    }

    float inv = 1.0f / l_run;
#pragma unroll
    for (int c = 0; c < 4; c++) {
        size_t oi = bhbase + (size_t)(n0 + r) * HD + g*4 + c;
        Or[oi] = accr[c] * inv;
        Oi[oi] = acci[c] * inv;
    }
}

// ---------------------------------------------------------------------------
// Final: y = Z + attn_out @ Wo^T + bo (complex), write stacked (2,B,N,D)
// grid (MM/64, DD/64), block (16,16).
// ---------------------------------------------------------------------------
__global__ __launch_bounds__(256) void final_kernel(
    const float* __restrict__ Or, const float* __restrict__ Oi,
    const float* __restrict__ wor, const float* __restrict__ woi,
    const float* __restrict__ bor, const float* __restrict__ boi,
    const float* __restrict__ Zr, const float* __restrict__ Zi,
    float* __restrict__ out)
{
    __shared__ float Xr_s[64][17], Xi_s[64][17], Wr_s[64][17], Wi_s[64][17];

    const int tx = threadIdx.x, ty = threadIdx.y;
    const int tid = ty * 16 + tx;
    const int m0 = blockIdx.x * 64, o0 = blockIdx.y * 64;

    float ar[4][4] = {}, ai[4][4] = {};

    for (int k0 = 0; k0 < DD; k0 += 16) {
        __syncthreads();
        for (int l = tid; l < 64 * 16; l += 256) {
            int row = l >> 4, kk = l & 15;
            int m = m0 + row;
            int b = m / NN, n = m % NN;
            int kg = k0 + kk;
            int h = kg >> 6, hd = kg & 63;
            size_t xidx = (((size_t)(b*HH + h))*NN + n)*HD + hd;
            size_t widx = (size_t)(o0 + row) * DD + kg;
            Xr_s[row][kk] = Or[xidx];
            Xi_s[row][kk] = Oi[xidx];
            Wr_s[row][kk] = wor[widx];
            Wi_s[row][kk] = woi[widx];
        }
        __syncthreads();
        for (int kk = 0; kk < 16; kk++) {
            float xr[4], xim[4], wre[4], wim[4];
#pragma unroll
            for (int i = 0; i < 4; i++) { xr[i]  = Xr_s[ty*4+i][kk]; xim[i] = Xi_s[ty*4+i][kk]; }
#pragma unroll
            for (int j = 0; j < 4; j++) { wre[j] = Wr_s[tx*4+j][kk]; wim[j] = Wi_s[tx*4+j][kk]; }
#pragma unroll
            for (int i = 0; i < 4; i++)
#pragma unroll
                for (int j = 0; j < 4; j++) {
                    ar[i][j] += xr[i]*wre[j] - xim[i]*wim[j];
                    ai[i][j] += xr[i]*wim[j] + xim[i]*wre[j];
                }
        }
    }

#pragma unroll
    for (int i = 0; i < 4; i++) {
        int m = m0 + ty*4 + i;
#pragma unroll
        for (int j = 0; j < 4; j++) {
            int o = o0 + tx*4 + j;
            size_t zi = (size_t)m * DD + o;
            out[zi] = ar[i][j] + bor[o] + Zr[zi];
            out[(size_t)MM * DD + zi] = ai[i][j] + boi[o] + Zi[zi];
        }
    }
}

// ---------------------------------------------------------------------------
extern "C" void kernel_launch(void* const* d_in, const int* in_sizes, int n_in,
                              void* d_out, int out_size, void* d_ws, size_t ws_size,
                              hipStream_t stream)
{
    const float* Zr  = (const float*)d_in[0];
    const float* Zi  = (const float*)d_in[1];
    const float* wqr = (const float*)d_in[2];
    const float* wqi = (const float*)d_in[3];
    const float* bqr = (const float*)d_in[4];
    const float* bqi = (const float*)d_in[5];
    const float* wkr = (const float*)d_in[6];
    const float* wki = (const float*)d_in[7];
    const float* bkr = (const float*)d_in[8];
    const float* bki = (const float*)d_in[9];
    const float* wvr = (const float*)d_in[10];
    const float* wvi = (const float*)d_in[11];
    const float* bvr = (const float*)d_in[12];
    const float* bvi = (const float*)d_in[13];
    const float* wor = (const float*)d_in[14];
    const float* woi = (const float*)d_in[15];
    const float* bor = (const float*)d_in[16];
    const float* boi = (const float*)d_in[17];
    const int*  mask = (const int*)d_in[18];

    float* ws = (float*)d_ws;
    const size_t PER = (size_t)BB * HH * NN * HD;   // 4,194,304 floats
    float* Qr = ws + 0 * PER;
    float* Qi = ws + 1 * PER;
    float* Kr = ws + 2 * PER;
    float* Ki = ws + 3 * PER;
    float* Vr = ws + 4 * PER;
    float* Vi = ws + 5 * PER;
    float* Ar = ws + 6 * PER;   // attention output
    float* Ai = ws + 7 * PER;

    dim3 gb(16, 16);
    proj_kernel<<<dim3(MM/64, DD/64, 3), gb, 0, stream>>>(
        Zr, Zi, wqr, wqi, bqr, bqi, wkr, wki, bkr, bki, wvr, wvi, bvr, bvi,
        Qr, Qi, Kr, Ki, Vr, Vi);

    attn_kernel<<<dim3(BB*HH*NQB), dim3(256), 0, stream>>>(
        Qr, Qi, Kr, Ki, Vr, Vi, mask, Ar, Ai);

    final_kernel<<<dim3(MM/64, DD/64), gb, 0, stream>>>(
        Ar, Ai, wor, woi, bor, boi, Zr, Zi, (float*)d_out);
}

// Round 2
// 454.153 us; speedup vs baseline: 12.9531x; 12.9531x over previous
//
#include <hip/hip_runtime.h>
#include <math.h>

#define BB 2
#define NN 2048
#define DD 1024
#define HH 16
#define HD 64
#define MM (BB*NN)          /* 4096 */
#define SCALE 0.125f

typedef __attribute__((ext_vector_type(8))) short bf16x8;
typedef __attribute__((ext_vector_type(4))) short bf16x4;
typedef __attribute__((ext_vector_type(4))) float f32x4;

#define MFMA(a,b,c) __builtin_amdgcn_mfma_f32_16x16x32_bf16(a,b,c,0,0,0)

__device__ __forceinline__ unsigned short f2bf(float x) {
    union { float f; unsigned u; } v; v.f = x;
    unsigned r = v.u + 0x7FFFu + ((v.u >> 16) & 1u);
    return (unsigned short)(r >> 16);
}

// LDS-safe 8-elem load/store as two b64s (rows are 8B-aligned, not 16B)
__device__ __forceinline__ bf16x8 ld8s(const short* p) {
    bf16x4 lo = *(const bf16x4*)p;
    bf16x4 hi = *(const bf16x4*)(p + 4);
    bf16x8 r;
    r[0]=lo[0]; r[1]=lo[1]; r[2]=lo[2]; r[3]=lo[3];
    r[4]=hi[0]; r[5]=hi[1]; r[6]=hi[2]; r[7]=hi[3];
    return r;
}
__device__ __forceinline__ void st8s(short* p, bf16x8 v) {
    bf16x4 lo, hi;
    lo[0]=v[0]; lo[1]=v[1]; lo[2]=v[2]; lo[3]=v[3];
    hi[0]=v[4]; hi[1]=v[5]; hi[2]=v[6]; hi[3]=v[7];
    *(bf16x4*)p = lo;
    *(bf16x4*)(p + 4) = hi;
}

// ---------------------------------------------------------------------------
// fp32 -> bf16 conversion (8 elems/thread)
// ---------------------------------------------------------------------------
__global__ void cvt_kernel(const float* __restrict__ in, unsigned short* __restrict__ out, int n) {
    int i = (blockIdx.x * blockDim.x + threadIdx.x) * 8;
    if (i >= n) return;
    float4 a = *(const float4*)(in + i);
    float4 b = *(const float4*)(in + i + 4);
    bf16x8 o;
    o[0]=(short)f2bf(a.x); o[1]=(short)f2bf(a.y); o[2]=(short)f2bf(a.z); o[3]=(short)f2bf(a.w);
    o[4]=(short)f2bf(b.x); o[5]=(short)f2bf(b.y); o[6]=(short)f2bf(b.z); o[7]=(short)f2bf(b.w);
    *(bf16x8*)(out + i) = o;
}

// ---------------------------------------------------------------------------
// Complex projection GEMM via MFMA. Y = Z @ W^T + b.
// grid (MM/128, DD/128, 3), block 256 (4 waves, each 64x64).
// z=0: Q head-major [b,h,n,hd]; z=1: K head-major, imag NEGATED;
// z=2: V transposed [b,h,hd,n].
// ---------------------------------------------------------------------------
__global__ __launch_bounds__(256) void proj_mfma(
    const unsigned short* __restrict__ Zr, const unsigned short* __restrict__ Zi,
    const unsigned short* __restrict__ Wqr, const unsigned short* __restrict__ Wqi,
    const unsigned short* __restrict__ Wkr, const unsigned short* __restrict__ Wki,
    const unsigned short* __restrict__ Wvr, const unsigned short* __restrict__ Wvi,
    const float* __restrict__ bqr, const float* __restrict__ bqi,
    const float* __restrict__ bkr, const float* __restrict__ bki,
    const float* __restrict__ bvr, const float* __restrict__ bvi,
    unsigned short* __restrict__ Qr, unsigned short* __restrict__ Qi,
    unsigned short* __restrict__ Kr, unsigned short* __restrict__ nKi,
    unsigned short* __restrict__ Vtr, unsigned short* __restrict__ Vti)
{
    const unsigned short *wr, *wi; const float *br, *bi;
    const int z = blockIdx.z;
    if (z == 0)      { wr = Wqr; wi = Wqi; br = bqr; bi = bqi; }
    else if (z == 1) { wr = Wkr; wi = Wki; br = bkr; bi = bki; }
    else             { wr = Wvr; wi = Wvi; br = bvr; bi = bvi; }

    __shared__ short Ar_s[128][40], Ai_s[128][40], Br_s[128][40], Bi_s[128][40];

    const int tid = threadIdx.x;
    const int lane = tid & 63, wave = tid >> 6;
    const int lr = lane & 15, lg = lane >> 4;
    const int wrow = (wave >> 1) * 64, wcol = (wave & 1) * 64;
    const int m0 = blockIdx.x * 128, o0 = blockIdx.y * 128;

    f32x4 accr[4][4], acci[4][4];
#pragma unroll
    for (int m = 0; m < 4; m++)
#pragma unroll
        for (int n = 0; n < 4; n++) {
            accr[m][n] = (f32x4){0.f,0.f,0.f,0.f};
            acci[m][n] = (f32x4){0.f,0.f,0.f,0.f};
        }

    for (int k0 = 0; k0 < DD; k0 += 32) {
        __syncthreads();
        for (int c = tid; c < 512; c += 256) {
            int row = c >> 2, ch = (c & 3) * 8;
            st8s(&Ar_s[row][ch], *(const bf16x8*)&Zr[(size_t)(m0 + row) * DD + k0 + ch]);
            st8s(&Ai_s[row][ch], *(const bf16x8*)&Zi[(size_t)(m0 + row) * DD + k0 + ch]);
            st8s(&Br_s[row][ch], *(const bf16x8*)&wr[(size_t)(o0 + row) * DD + k0 + ch]);
            st8s(&Bi_s[row][ch], *(const bf16x8*)&wi[(size_t)(o0 + row) * DD + k0 + ch]);
        }
        __syncthreads();

        bf16x8 ar[4], ai[4], nai[4], brf[4], bif[4];
#pragma unroll
        for (int m = 0; m < 4; m++) {
            ar[m]  = ld8s(&Ar_s[wrow + m*16 + lr][lg*8]);
            ai[m]  = ld8s(&Ai_s[wrow + m*16 + lr][lg*8]);
            nai[m] = ai[m] ^ (short)0x8000;
        }
#pragma unroll
        for (int n = 0; n < 4; n++) {
            brf[n] = ld8s(&Br_s[wcol + n*16 + lr][lg*8]);
            bif[n] = ld8s(&Bi_s[wcol + n*16 + lr][lg*8]);
        }
#pragma unroll
        for (int m = 0; m < 4; m++)
#pragma unroll
            for (int n = 0; n < 4; n++) {
                accr[m][n] = MFMA(ar[m],  brf[n], accr[m][n]);
                accr[m][n] = MFMA(nai[m], bif[n], accr[m][n]);
                acci[m][n] = MFMA(ar[m],  bif[n], acci[m][n]);
                acci[m][n] = MFMA(ai[m],  brf[n], acci[m][n]);
            }
    }

#pragma unroll
    for (int mi = 0; mi < 4; mi++) {
#pragma unroll
        for (int nj = 0; nj < 4; nj++) {
            const int o = o0 + wcol + nj*16 + lr;
            const int h = o >> 6, hd = o & 63;
            const float brv = br[o], biv = bi[o];
            if (z == 2) {
                bf16x4 pr4, pi4;
#pragma unroll
                for (int reg = 0; reg < 4; reg++) {
                    pr4[reg] = (short)f2bf(accr[mi][nj][reg] + brv);
                    pi4[reg] = (short)f2bf(acci[mi][nj][reg] + biv);
                }
                const int m = m0 + wrow + mi*16 + lg*4;
                const int b = m >> 11, n = m & (NN - 1);
                size_t base = ((size_t)((b*HH + h)*HD + hd)) * NN + n;
                *(bf16x4*)&Vtr[base] = pr4;
                *(bf16x4*)&Vti[base] = pi4;
            } else {
#pragma unroll
                for (int reg = 0; reg < 4; reg++) {
                    const int m = m0 + wrow + mi*16 + lg*4 + reg;
                    const int b = m >> 11, n = m & (NN - 1);
                    size_t idx = ((size_t)((b*HH + h)*NN + n)) * HD + hd;
                    float vr = accr[mi][nj][reg] + brv;
                    float vi2 = acci[mi][nj][reg] + biv;
                    if (z == 0) { Qr[idx] = f2bf(vr); Qi[idx] = f2bf(vi2); }
                    else        { Kr[idx] = f2bf(vr); nKi[idx] = f2bf(-vi2); }
                }
            }
        }
    }
}

// ---------------------------------------------------------------------------
// MFMA flash attention. grid (NN/64, HH, BB), block 256 (4 waves x 16 q-rows).
// scores = Qr.Kr^T + Qi.(-Ki)^T (nKi pre-negated), mask-replace -1e9,
// online softmax in-register, PV via bf16 P staged in per-wave LDS.
// Output bf16 row-major [b*N+n][h*64+hd] for the final GEMM.
// ---------------------------------------------------------------------------
#define LDK 72
__global__ __launch_bounds__(256) void attn_mfma(
    const unsigned short* __restrict__ Qr, const unsigned short* __restrict__ Qi,
    const unsigned short* __restrict__ Kr, const unsigned short* __restrict__ nKi,
    const unsigned short* __restrict__ Vtr, const unsigned short* __restrict__ Vti,
    const int* __restrict__ mask,
    unsigned short* __restrict__ Aor, unsigned short* __restrict__ Aoi)
{
    __shared__ short Kr_s[64][LDK], Ki_s[64][LDK], Vr_s[64][LDK], Vi_s[64][LDK];
    __shared__ short P_s[4][16][LDK];
    __shared__ float smask[64];

    const int tid = threadIdx.x;
    const int lane = tid & 63, wave = tid >> 6;
    const int lr = lane & 15, lg = lane >> 4;
    const int h = blockIdx.y, b = blockIdx.z;
    const int n0 = blockIdx.x * 64 + wave * 16;
    const size_t qkb = ((size_t)(b*HH + h)) * NN * HD;
    const size_t vb  = ((size_t)(b*HH + h)) * HD * NN;

    bf16x8 qr[2], qi[2];
#pragma unroll
    for (int kf = 0; kf < 2; kf++) {
        qr[kf] = *(const bf16x8*)&Qr[qkb + (size_t)(n0 + lr) * HD + kf*32 + lg*8];
        qi[kf] = *(const bf16x8*)&Qi[qkb + (size_t)(n0 + lr) * HD + kf*32 + lg*8];
    }

    f32x4 o_r[4], o_i[4];
#pragma unroll
    for (int nf = 0; nf < 4; nf++) { o_r[nf] = (f32x4){0.f,0.f,0.f,0.f}; o_i[nf] = (f32x4){0.f,0.f,0.f,0.f}; }
    float m_run[4], l_run[4];
#pragma unroll
    for (int r = 0; r < 4; r++) { m_run[r] = -3.0e38f; l_run[r] = 0.0f; }

    for (int t0 = 0; t0 < NN; t0 += 64) {
        __syncthreads();
        for (int c = tid; c < 512; c += 256) {
            int row = c >> 3, ch = (c & 7) * 8;
            st8s(&Kr_s[row][ch], *(const bf16x8*)&Kr [qkb + (size_t)(t0 + row) * HD + ch]);
            st8s(&Ki_s[row][ch], *(const bf16x8*)&nKi[qkb + (size_t)(t0 + row) * HD + ch]);
            st8s(&Vr_s[row][ch], *(const bf16x8*)&Vtr[vb + (size_t)row * NN + t0 + ch]);
            st8s(&Vi_s[row][ch], *(const bf16x8*)&Vti[vb + (size_t)row * NN + t0 + ch]);
        }
        if (tid < 64) smask[tid] = (float)mask[b * NN + t0 + tid];
        __syncthreads();

        // ---- scores: 16x64 per wave ----
        f32x4 sacc[4];
#pragma unroll
        for (int nf = 0; nf < 4; nf++) {
            sacc[nf] = (f32x4){0.f,0.f,0.f,0.f};
            bf16x8 k0f = ld8s(&Kr_s[nf*16 + lr][lg*8]);
            bf16x8 k1f = ld8s(&Kr_s[nf*16 + lr][32 + lg*8]);
            bf16x8 i0f = ld8s(&Ki_s[nf*16 + lr][lg*8]);
            bf16x8 i1f = ld8s(&Ki_s[nf*16 + lr][32 + lg*8]);
            sacc[nf] = MFMA(qr[0], k0f, sacc[nf]);
            sacc[nf] = MFMA(qr[1], k1f, sacc[nf]);
            sacc[nf] = MFMA(qi[0], i0f, sacc[nf]);
            sacc[nf] = MFMA(qi[1], i1f, sacc[nf]);
        }

        // ---- mask + online softmax (rows = lg*4+reg, cols = nf*16+lr) ----
        float sv[4][4], rowmax[4];
#pragma unroll
        for (int r = 0; r < 4; r++) rowmax[r] = -3.0e38f;
#pragma unroll
        for (int nf = 0; nf < 4; nf++) {
            float mk = smask[nf*16 + lr];
#pragma unroll
            for (int reg = 0; reg < 4; reg++) {
                float v = (mk == 0.0f) ? -1e9f : sacc[nf][reg] * SCALE;
                sv[nf][reg] = v;
                rowmax[reg] = fmaxf(rowmax[reg], v);
            }
        }
        float fac[4], psum[4];
#pragma unroll
        for (int reg = 0; reg < 4; reg++) {
            float v = rowmax[reg];
            v = fmaxf(v, __shfl_xor(v, 1, 64));
            v = fmaxf(v, __shfl_xor(v, 2, 64));
            v = fmaxf(v, __shfl_xor(v, 4, 64));
            v = fmaxf(v, __shfl_xor(v, 8, 64));
            float mn = fmaxf(m_run[reg], v);
            fac[reg] = __expf(m_run[reg] - mn);
            m_run[reg] = mn;
            psum[reg] = 0.0f;
        }
#pragma unroll
        for (int nf = 0; nf < 4; nf++)
#pragma unroll
            for (int reg = 0; reg < 4; reg++) {
                float p = __expf(sv[nf][reg] - m_run[reg]);
                psum[reg] += p;
                P_s[wave][lg*4 + reg][nf*16 + lr] = (short)f2bf(p);
            }
#pragma unroll
        for (int reg = 0; reg < 4; reg++) {
            float ps = psum[reg];
            ps += __shfl_xor(ps, 1, 64);
            ps += __shfl_xor(ps, 2, 64);
            ps += __shfl_xor(ps, 4, 64);
            ps += __shfl_xor(ps, 8, 64);
            l_run[reg] = l_run[reg] * fac[reg] + ps;
        }
#pragma unroll
        for (int nf = 0; nf < 4; nf++)
#pragma unroll
            for (int reg = 0; reg < 4; reg++) {
                o_r[nf][reg] *= fac[reg];
                o_i[nf][reg] *= fac[reg];
            }
        __syncthreads();   // P_s visibility (cross-lane within wave)

        // ---- PV ----
        bf16x8 pa0 = ld8s(&P_s[wave][lr][lg*8]);
        bf16x8 pa1 = ld8s(&P_s[wave][lr][32 + lg*8]);
#pragma unroll
        for (int nf = 0; nf < 4; nf++) {
            bf16x8 v0 = ld8s(&Vr_s[nf*16 + lr][lg*8]);
            bf16x8 v1 = ld8s(&Vr_s[nf*16 + lr][32 + lg*8]);
            bf16x8 w0 = ld8s(&Vi_s[nf*16 + lr][lg*8]);
            bf16x8 w1 = ld8s(&Vi_s[nf*16 + lr][32 + lg*8]);
            o_r[nf] = MFMA(pa0, v0, o_r[nf]);
            o_r[nf] = MFMA(pa1, v1, o_r[nf]);
            o_i[nf] = MFMA(pa0, w0, o_i[nf]);
            o_i[nf] = MFMA(pa1, w1, o_i[nf]);
        }
    }

    float invl[4];
#pragma unroll
    for (int reg = 0; reg < 4; reg++) invl[reg] = 1.0f / l_run[reg];
#pragma unroll
    for (int nf = 0; nf < 4; nf++)
#pragma unroll
        for (int reg = 0; reg < 4; reg++) {
            int row = n0 + lg*4 + reg;
            int kk = h*HD + nf*16 + lr;
            size_t idx = ((size_t)(b*NN + row)) * DD + kk;
            Aor[idx] = f2bf(o_r[nf][reg] * invl[reg]);
            Aoi[idx] = f2bf(o_i[nf][reg] * invl[reg]);
        }
}

// ---------------------------------------------------------------------------
// Final complex GEMM + bias + residual, fp32 out stacked (2,B,N,D).
// grid (MM/128, DD/128), block 256.
// ---------------------------------------------------------------------------
__global__ __launch_bounds__(256) void final_mfma(
    const unsigned short* __restrict__ Ar, const unsigned short* __restrict__ Ai,
    const unsigned short* __restrict__ Wor, const unsigned short* __restrict__ Woi,
    const float* __restrict__ bor, const float* __restrict__ boi,
    const float* __restrict__ Zr, const float* __restrict__ Zi,
    float* __restrict__ out)
{
    __shared__ short Ar_s[128][40], Ai_s[128][40], Br_s[128][40], Bi_s[128][40];

    const int tid = threadIdx.x;
    const int lane = tid & 63, wave = tid >> 6;
    const int lr = lane & 15, lg = lane >> 4;
    const int wrow = (wave >> 1) * 64, wcol = (wave & 1) * 64;
    const int m0 = blockIdx.x * 128, o0 = blockIdx.y * 128;

    f32x4 accr[4][4], acci[4][4];
#pragma unroll
    for (int m = 0; m < 4; m++)
#pragma unroll
        for (int n = 0; n < 4; n++) {
            accr[m][n] = (f32x4){0.f,0.f,0.f,0.f};
            acci[m][n] = (f32x4){0.f,0.f,0.f,0.f};
        }

    for (int k0 = 0; k0 < DD; k0 += 32) {
        __syncthreads();
        for (int c = tid; c < 512; c += 256) {
            int row = c >> 2, ch = (c & 3) * 8;
            st8s(&Ar_s[row][ch], *(const bf16x8*)&Ar[(size_t)(m0 + row) * DD + k0 + ch]);
            st8s(&Ai_s[row][ch], *(const bf16x8*)&Ai[(size_t)(m0 + row) * DD + k0 + ch]);
            st8s(&Br_s[row][ch], *(const bf16x8*)&Wor[(size_t)(o0 + row) * DD + k0 + ch]);
            st8s(&Bi_s[row][ch], *(const bf16x8*)&Woi[(size_t)(o0 + row) * DD + k0 + ch]);
        }
        __syncthreads();

        bf16x8 ar[4], ai[4], nai[4], brf[4], bif[4];
#pragma unroll
        for (int m = 0; m < 4; m++) {
            ar[m]  = ld8s(&Ar_s[wrow + m*16 + lr][lg*8]);
            ai[m]  = ld8s(&Ai_s[wrow + m*16 + lr][lg*8]);
            nai[m] = ai[m] ^ (short)0x8000;
        }
#pragma unroll
        for (int n = 0; n < 4; n++) {
            brf[n] = ld8s(&Br_s[wcol + n*16 + lr][lg*8]);
            bif[n] = ld8s(&Bi_s[wcol + n*16 + lr][lg*8]);
        }
#pragma unroll
        for (int m = 0; m < 4; m++)
#pragma unroll
            for (int n = 0; n < 4; n++) {
                accr[m][n] = MFMA(ar[m],  brf[n], accr[m][n]);
                accr[m][n] = MFMA(nai[m], bif[n], accr[m][n]);
                acci[m][n] = MFMA(ar[m],  bif[n], acci[m][n]);
                acci[m][n] = MFMA(ai[m],  brf[n], acci[m][n]);
            }
    }

#pragma unroll
    for (int mi = 0; mi < 4; mi++)
#pragma unroll
        for (int nj = 0; nj < 4; nj++) {
            const int o = o0 + wcol + nj*16 + lr;
            const float brv = bor[o], biv = boi[o];
#pragma unroll
            for (int reg = 0; reg < 4; reg++) {
                const int m = m0 + wrow + mi*16 + lg*4 + reg;
                size_t zi = (size_t)m * DD + o;
                out[zi] = accr[mi][nj][reg] + brv + Zr[zi];
                out[(size_t)MM * DD + zi] = acci[mi][nj][reg] + biv + Zi[zi];
            }
        }
}

// ---------------------------------------------------------------------------
extern "C" void kernel_launch(void* const* d_in, const int* in_sizes, int n_in,
                              void* d_out, int out_size, void* d_ws, size_t ws_size,
                              hipStream_t stream)
{
    const float* Zr  = (const float*)d_in[0];
    const float* Zi  = (const float*)d_in[1];
    const float* wqr = (const float*)d_in[2];
    const float* wqi = (const float*)d_in[3];
    const float* bqr = (const float*)d_in[4];
    const float* bqi = (const float*)d_in[5];
    const float* wkr = (const float*)d_in[6];
    const float* wki = (const float*)d_in[7];
    const float* bkr = (const float*)d_in[8];
    const float* bki = (const float*)d_in[9];
    const float* wvr = (const float*)d_in[10];
    const float* wvi = (const float*)d_in[11];
    const float* bvr = (const float*)d_in[12];
    const float* bvi = (const float*)d_in[13];
    const float* wor = (const float*)d_in[14];
    const float* woi = (const float*)d_in[15];
    const float* bor = (const float*)d_in[16];
    const float* boi = (const float*)d_in[17];
    const int*  mask = (const int*)d_in[18];

    unsigned short* w16 = (unsigned short*)d_ws;
    const size_t ZN = (size_t)MM * DD;   // 4,194,304
    const size_t WN = (size_t)DD * DD;   // 1,048,576
    unsigned short* Zr16  = w16;              unsigned short* Zi16  = Zr16 + ZN;
    unsigned short* Wqr16 = Zi16 + ZN;        unsigned short* Wqi16 = Wqr16 + WN;
    unsigned short* Wkr16 = Wqi16 + WN;       unsigned short* Wki16 = Wkr16 + WN;
    unsigned short* Wvr16 = Wki16 + WN;       unsigned short* Wvi16 = Wvr16 + WN;
    unsigned short* Wor16 = Wvi16 + WN;       unsigned short* Woi16 = Wor16 + WN;
    unsigned short* Qr16  = Woi16 + WN;       unsigned short* Qi16  = Qr16 + ZN;
    unsigned short* Kr16  = Qi16 + ZN;        unsigned short* nKi16 = Kr16 + ZN;
    unsigned short* Vtr16 = nKi16 + ZN;       unsigned short* Vti16 = Vtr16 + ZN;
    unsigned short* Aor16 = Vti16 + ZN;       unsigned short* Aoi16 = Aor16 + ZN;

    cvt_kernel<<<(int)(ZN/2048), 256, 0, stream>>>(Zr,  Zr16,  (int)ZN);
    cvt_kernel<<<(int)(ZN/2048), 256, 0, stream>>>(Zi,  Zi16,  (int)ZN);
    cvt_kernel<<<(int)(WN/2048), 256, 0, stream>>>(wqr, Wqr16, (int)WN);
    cvt_kernel<<<(int)(WN/2048), 256, 0, stream>>>(wqi, Wqi16, (int)WN);
    cvt_kernel<<<(int)(WN/2048), 256, 0, stream>>>(wkr, Wkr16, (int)WN);
    cvt_kernel<<<(int)(WN/2048), 256, 0, stream>>>(wki, Wki16, (int)WN);
    cvt_kernel<<<(int)(WN/2048), 256, 0, stream>>>(wvr, Wvr16, (int)WN);
    cvt_kernel<<<(int)(WN/2048), 256, 0, stream>>>(wvi, Wvi16, (int)WN);
    cvt_kernel<<<(int)(WN/2048), 256, 0, stream>>>(wor, Wor16, (int)WN);
    cvt_kernel<<<(int)(WN/2048), 256, 0, stream>>>(woi, Woi16, (int)WN);

    proj_mfma<<<dim3(MM/128, DD/128, 3), 256, 0, stream>>>(
        Zr16, Zi16, Wqr16, Wqi16, Wkr16, Wki16, Wvr16, Wvi16,
        bqr, bqi, bkr, bki, bvr, bvi,
        Qr16, Qi16, Kr16, nKi16, Vtr16, Vti16);

    attn_mfma<<<dim3(NN/64, HH, BB), 256, 0, stream>>>(
        Qr16, Qi16, Kr16, nKi16, Vtr16, Vti16, mask, Aor16, Aoi16);

    final_mfma<<<dim3(MM/128, DD/128), 256, 0, stream>>>(
        Aor16, Aoi16, Wor16, Woi16, bor, boi, Zr, Zi, (float*)d_out);
}

// Round 3
// 341.784 us; speedup vs baseline: 17.2117x; 1.3288x over previous
//
#include <hip/hip_runtime.h>
#include <math.h>

#define BB 2
#define NN 2048
#define DD 1024
#define HH 16
#define HD 64
#define MM (BB*NN)          /* 4096 */
#define SCALE 0.125f

typedef __attribute__((ext_vector_type(8))) short bf16x8;
typedef __attribute__((ext_vector_type(4))) short bf16x4;
typedef __attribute__((ext_vector_type(4))) float f32x4;

#define MFMA(a,b,c) __builtin_amdgcn_mfma_f32_16x16x32_bf16(a,b,c,0,0,0)

__device__ __forceinline__ unsigned short f2bf(float x) {
    union { float f; unsigned u; } v; v.f = x;
    unsigned r = v.u + 0x7FFFu + ((v.u >> 16) & 1u);
    return (unsigned short)(r >> 16);
}

__device__ __forceinline__ bf16x8 ld8s(const short* p) {
    bf16x4 lo = *(const bf16x4*)p;
    bf16x4 hi = *(const bf16x4*)(p + 4);
    bf16x8 r;
    r[0]=lo[0]; r[1]=lo[1]; r[2]=lo[2]; r[3]=lo[3];
    r[4]=hi[0]; r[5]=hi[1]; r[6]=hi[2]; r[7]=hi[3];
    return r;
}
__device__ __forceinline__ void st8s(short* p, bf16x8 v) {
    bf16x4 lo, hi;
    lo[0]=v[0]; lo[1]=v[1]; lo[2]=v[2]; lo[3]=v[3];
    hi[0]=v[4]; hi[1]=v[5]; hi[2]=v[6]; hi[3]=v[7];
    *(bf16x4*)p = lo;
    *(bf16x4*)(p + 4) = hi;
}

// ---------------------------------------------------------------------------
// Per-batch mask prefix scan -> compact index list + count. grid BB, 256 thr.
// ---------------------------------------------------------------------------
__global__ __launch_bounds__(256) void mask_scan(const int* __restrict__ mask,
                                                 int* __restrict__ idxArr,
                                                 int* __restrict__ cntArr)
{
    const int b = blockIdx.x, t = threadIdx.x;
    __shared__ int part[256];
    int m[8]; int c = 0;
#pragma unroll
    for (int j = 0; j < 8; j++) { m[j] = mask[b*NN + t*8 + j]; c += (m[j] != 0); }
    part[t] = c; __syncthreads();
    for (int off = 1; off < 256; off <<= 1) {
        int v = (t >= off) ? part[t - off] : 0;
        __syncthreads();
        part[t] += v;
        __syncthreads();
    }
    int base = part[t] - c;
    int total = part[255];
#pragma unroll
    for (int j = 0; j < 8; j++) if (m[j]) idxArr[b*NN + base++] = t*8 + j;
    for (int p = total + t; p < NN; p += 256) idxArr[b*NN + p] = 0;
    if (t == 0) cntArr[b] = total;
}

// ---------------------------------------------------------------------------
// Fused fp32->bf16 conversion for Z (2 x 4.2M) + 8 weights (1.05M each).
// grid 8192 x 256, 8 elems/thread, 2048 elems/block.
// ---------------------------------------------------------------------------
__global__ __launch_bounds__(256) void cvt_fused(
    const float* __restrict__ Zr, const float* __restrict__ Zi,
    const float* __restrict__ wqr, const float* __restrict__ wqi,
    const float* __restrict__ wkr, const float* __restrict__ wki,
    const float* __restrict__ wvr, const float* __restrict__ wvi,
    const float* __restrict__ wor, const float* __restrict__ woi,
    unsigned short* __restrict__ dZr, unsigned short* __restrict__ dZi,
    unsigned short* __restrict__ dwqr, unsigned short* __restrict__ dwqi,
    unsigned short* __restrict__ dwkr, unsigned short* __restrict__ dwki,
    unsigned short* __restrict__ dwvr, unsigned short* __restrict__ dwvi,
    unsigned short* __restrict__ dwor, unsigned short* __restrict__ dwoi)
{
    const int bid = blockIdx.x;
    const float* s; unsigned short* d; size_t off;
    if (bid < 2048)      { s = Zr; d = dZr; off = (size_t)bid * 2048; }
    else if (bid < 4096) { s = Zi; d = dZi; off = (size_t)(bid - 2048) * 2048; }
    else {
        int w = (bid - 4096) >> 9, r = (bid - 4096) & 511;
        off = (size_t)r * 2048;
        switch (w) {
            case 0: s = wqr; d = dwqr; break;
            case 1: s = wqi; d = dwqi; break;
            case 2: s = wkr; d = dwkr; break;
            case 3: s = wki; d = dwki; break;
            case 4: s = wvr; d = dwvr; break;
            case 5: s = wvi; d = dwvi; break;
            case 6: s = wor; d = dwor; break;
            default: s = woi; d = dwoi; break;
        }
    }
    size_t i = off + (size_t)threadIdx.x * 8;
    float4 a = *(const float4*)(s + i);
    float4 b4 = *(const float4*)(s + i + 4);
    bf16x8 o;
    o[0]=(short)f2bf(a.x); o[1]=(short)f2bf(a.y); o[2]=(short)f2bf(a.z); o[3]=(short)f2bf(a.w);
    o[4]=(short)f2bf(b4.x); o[5]=(short)f2bf(b4.y); o[6]=(short)f2bf(b4.z); o[7]=(short)f2bf(b4.w);
    *(bf16x8*)(d + i) = o;
}

// ---------------------------------------------------------------------------
// Q projection: Q = (Z @ Wq^T + bq) * SCALE, head-major bf16.
// grid (MM/128, DD/128), block 256 (4 waves, each 64x64).
// ---------------------------------------------------------------------------
__global__ __launch_bounds__(256) void proj_q(
    const unsigned short* __restrict__ Zr, const unsigned short* __restrict__ Zi,
    const unsigned short* __restrict__ Wr, const unsigned short* __restrict__ Wi,
    const float* __restrict__ br, const float* __restrict__ bi,
    unsigned short* __restrict__ Qr, unsigned short* __restrict__ Qi)
{
    __shared__ short Ar_s[128][40], Ai_s[128][40], Br_s[128][40], Bi_s[128][40];

    const int tid = threadIdx.x;
    const int lane = tid & 63, wave = tid >> 6;
    const int lr = lane & 15, lg = lane >> 4;
    const int wrow = (wave >> 1) * 64, wcol = (wave & 1) * 64;
    const int m0 = blockIdx.x * 128, o0 = blockIdx.y * 128;

    f32x4 accr[4][4], acci[4][4];
#pragma unroll
    for (int m = 0; m < 4; m++)
#pragma unroll
        for (int n = 0; n < 4; n++) {
            accr[m][n] = (f32x4){0.f,0.f,0.f,0.f};
            acci[m][n] = (f32x4){0.f,0.f,0.f,0.f};
        }

    for (int k0 = 0; k0 < DD; k0 += 32) {
        __syncthreads();
        for (int c = tid; c < 512; c += 256) {
            int row = c >> 2, ch = (c & 3) * 8;
            st8s(&Ar_s[row][ch], *(const bf16x8*)&Zr[(size_t)(m0 + row) * DD + k0 + ch]);
            st8s(&Ai_s[row][ch], *(const bf16x8*)&Zi[(size_t)(m0 + row) * DD + k0 + ch]);
            st8s(&Br_s[row][ch], *(const bf16x8*)&Wr[(size_t)(o0 + row) * DD + k0 + ch]);
            st8s(&Bi_s[row][ch], *(const bf16x8*)&Wi[(size_t)(o0 + row) * DD + k0 + ch]);
        }
        __syncthreads();

        bf16x8 ar[4], ai[4], nai[4], brf[4], bif[4];
#pragma unroll
        for (int m = 0; m < 4; m++) {
            ar[m]  = ld8s(&Ar_s[wrow + m*16 + lr][lg*8]);
            ai[m]  = ld8s(&Ai_s[wrow + m*16 + lr][lg*8]);
            nai[m] = ai[m] ^ (short)0x8000;
        }
#pragma unroll
        for (int n = 0; n < 4; n++) {
            brf[n] = ld8s(&Br_s[wcol + n*16 + lr][lg*8]);
            bif[n] = ld8s(&Bi_s[wcol + n*16 + lr][lg*8]);
        }
#pragma unroll
        for (int m = 0; m < 4; m++)
#pragma unroll
            for (int n = 0; n < 4; n++) {
                accr[m][n] = MFMA(ar[m],  brf[n], accr[m][n]);
                accr[m][n] = MFMA(nai[m], bif[n], accr[m][n]);
                acci[m][n] = MFMA(ar[m],  bif[n], acci[m][n]);
                acci[m][n] = MFMA(ai[m],  brf[n], acci[m][n]);
            }
    }

#pragma unroll
    for (int mi = 0; mi < 4; mi++)
#pragma unroll
        for (int nj = 0; nj < 4; nj++) {
            const int o = o0 + wcol + nj*16 + lr;
            const int h = o >> 6, hd = o & 63;
            const float brv = br[o], biv = bi[o];
#pragma unroll
            for (int reg = 0; reg < 4; reg++) {
                const int m = m0 + wrow + mi*16 + lg*4 + reg;
                const int b = m >> 11, n = m & (NN - 1);
                size_t idx = ((size_t)((b*HH + h)*NN + n)) * HD + hd;
                Qr[idx] = f2bf((accr[mi][nj][reg] + brv) * SCALE);
                Qi[idx] = f2bf((acci[mi][nj][reg] + biv) * SCALE);
            }
        }
}

// ---------------------------------------------------------------------------
// K/V projection over COMPACTED (unmasked) key rows, gathered via idxArr.
// grid (NN/128, DD/128, BB*2): z = b*2 + which (0=K, 1=V).
// K out: head-major [b,h,jc,hd], imag negated. V out: transposed [b,h,hd,jc].
// ---------------------------------------------------------------------------
__global__ __launch_bounds__(256) void proj_kv(
    const unsigned short* __restrict__ Zr, const unsigned short* __restrict__ Zi,
    const unsigned short* __restrict__ Wkr, const unsigned short* __restrict__ Wki,
    const unsigned short* __restrict__ Wvr, const unsigned short* __restrict__ Wvi,
    const float* __restrict__ bkr, const float* __restrict__ bki,
    const float* __restrict__ bvr, const float* __restrict__ bvi,
    const int* __restrict__ idxArr, const int* __restrict__ cntArr,
    unsigned short* __restrict__ Krc, unsigned short* __restrict__ nKic,
    unsigned short* __restrict__ Vtr, unsigned short* __restrict__ Vti)
{
    const int bz = blockIdx.z;
    const int b = bz >> 1, which = bz & 1;
    const int cnt = cntArr[b];
    const int m0 = blockIdx.x * 128;
    if (m0 >= ((cnt + 63) & ~63)) return;

    const unsigned short* wr = which ? Wvr : Wkr;
    const unsigned short* wi = which ? Wvi : Wki;
    const float* br = which ? bvr : bkr;
    const float* bi = which ? bvi : bki;

    __shared__ short Ar_s[128][40], Ai_s[128][40], Br_s[128][40], Bi_s[128][40];
    __shared__ int idx_s[128];

    const int tid = threadIdx.x;
    const int lane = tid & 63, wave = tid >> 6;
    const int lr = lane & 15, lg = lane >> 4;
    const int wrow = (wave >> 1) * 64, wcol = (wave & 1) * 64;
    const int o0 = blockIdx.y * 128;

    if (tid < 128) idx_s[tid] = idxArr[b*NN + m0 + tid];

    f32x4 accr[4][4], acci[4][4];
#pragma unroll
    for (int m = 0; m < 4; m++)
#pragma unroll
        for (int n = 0; n < 4; n++) {
            accr[m][n] = (f32x4){0.f,0.f,0.f,0.f};
            acci[m][n] = (f32x4){0.f,0.f,0.f,0.f};
        }

    for (int k0 = 0; k0 < DD; k0 += 32) {
        __syncthreads();
        for (int c = tid; c < 512; c += 256) {
            int row = c >> 2, ch = (c & 3) * 8;
            size_t zrow = (size_t)(b*NN + idx_s[row]);
            st8s(&Ar_s[row][ch], *(const bf16x8*)&Zr[zrow * DD + k0 + ch]);
            st8s(&Ai_s[row][ch], *(const bf16x8*)&Zi[zrow * DD + k0 + ch]);
            st8s(&Br_s[row][ch], *(const bf16x8*)&wr[(size_t)(o0 + row) * DD + k0 + ch]);
            st8s(&Bi_s[row][ch], *(const bf16x8*)&wi[(size_t)(o0 + row) * DD + k0 + ch]);
        }
        __syncthreads();

        bf16x8 ar[4], ai[4], nai[4], brf[4], bif[4];
#pragma unroll
        for (int m = 0; m < 4; m++) {
            ar[m]  = ld8s(&Ar_s[wrow + m*16 + lr][lg*8]);
            ai[m]  = ld8s(&Ai_s[wrow + m*16 + lr][lg*8]);
            nai[m] = ai[m] ^ (short)0x8000;
        }
#pragma unroll
        for (int n = 0; n < 4; n++) {
            brf[n] = ld8s(&Br_s[wcol + n*16 + lr][lg*8]);
            bif[n] = ld8s(&Bi_s[wcol + n*16 + lr][lg*8]);
        }
#pragma unroll
        for (int m = 0; m < 4; m++)
#pragma unroll
            for (int n = 0; n < 4; n++) {
                accr[m][n] = MFMA(ar[m],  brf[n], accr[m][n]);
                accr[m][n] = MFMA(nai[m], bif[n], accr[m][n]);
                acci[m][n] = MFMA(ar[m],  bif[n], acci[m][n]);
                acci[m][n] = MFMA(ai[m],  brf[n], acci[m][n]);
            }
    }

#pragma unroll
    for (int mi = 0; mi < 4; mi++)
#pragma unroll
        for (int nj = 0; nj < 4; nj++) {
            const int o = o0 + wcol + nj*16 + lr;
            const int h = o >> 6, hd = o & 63;
            const float brv = br[o], biv = bi[o];
            if (which) {   // V: transposed store [b,h,hd,jc]
                bf16x4 pr4, pi4;
#pragma unroll
                for (int reg = 0; reg < 4; reg++) {
                    pr4[reg] = (short)f2bf(accr[mi][nj][reg] + brv);
                    pi4[reg] = (short)f2bf(acci[mi][nj][reg] + biv);
                }
                const int jc = m0 + wrow + mi*16 + lg*4;
                size_t base = ((size_t)((b*HH + h)*HD + hd)) * NN + jc;
                *(bf16x4*)&Vtr[base] = pr4;
                *(bf16x4*)&Vti[base] = pi4;
            } else {       // K: head-major [b,h,jc,hd], imag negated
#pragma unroll
                for (int reg = 0; reg < 4; reg++) {
                    const int jc = m0 + wrow + mi*16 + lg*4 + reg;
                    size_t idx = ((size_t)((b*HH + h)*NN + jc)) * HD + hd;
                    Krc[idx]  = f2bf(accr[mi][nj][reg] + brv);
                    nKic[idx] = f2bf(-(acci[mi][nj][reg] + biv));
                }
            }
        }
}

// ---------------------------------------------------------------------------
// MFMA flash attention over compacted keys. grid (NN/128, HH, BB), block 256
// (4 waves x 32 q-rows). Scores pre-scaled (Q carries SCALE). Tail tile
// masked to -1e9 (exp underflows to 0 exactly, matching reference).
// ---------------------------------------------------------------------------
#define LDP 72
__global__ __launch_bounds__(256) void attn_mfma(
    const unsigned short* __restrict__ Qr, const unsigned short* __restrict__ Qi,
    const unsigned short* __restrict__ Krc, const unsigned short* __restrict__ nKic,
    const unsigned short* __restrict__ Vtc, const unsigned short* __restrict__ Vtic,
    const int* __restrict__ cntArr,
    unsigned short* __restrict__ Aor, unsigned short* __restrict__ Aoi)
{
    __shared__ short Kr_s[64][LDP], Ki_s[64][LDP], Vr_s[64][LDP], Vi_s[64][LDP];
    __shared__ short P_s[4][32][LDP];

    const int tid = threadIdx.x;
    const int lane = tid & 63, wave = tid >> 6;
    const int lr = lane & 15, lg = lane >> 4;
    const int h = blockIdx.y, b = blockIdx.z;
    const int n0 = blockIdx.x * 128 + wave * 32;
    const size_t qb = ((size_t)(b*HH + h)) * NN * HD;
    const int cnt = cntArr[b];
    const int ct = (cnt + 63) & ~63;

    bf16x8 qr[2][2], qi[2][2];
#pragma unroll
    for (int mf = 0; mf < 2; mf++)
#pragma unroll
        for (int kf = 0; kf < 2; kf++) {
            qr[mf][kf] = *(const bf16x8*)&Qr[qb + (size_t)(n0 + mf*16 + lr) * HD + kf*32 + lg*8];
            qi[mf][kf] = *(const bf16x8*)&Qi[qb + (size_t)(n0 + mf*16 + lr) * HD + kf*32 + lg*8];
        }

    f32x4 o_r[2][4], o_i[2][4];
#pragma unroll
    for (int mf = 0; mf < 2; mf++)
#pragma unroll
        for (int nf = 0; nf < 4; nf++) {
            o_r[mf][nf] = (f32x4){0.f,0.f,0.f,0.f};
            o_i[mf][nf] = (f32x4){0.f,0.f,0.f,0.f};
        }
    float m_run[2][4], l_run[2][4];
#pragma unroll
    for (int mf = 0; mf < 2; mf++)
#pragma unroll
        for (int r = 0; r < 4; r++) { m_run[mf][r] = -3.0e38f; l_run[mf][r] = 0.0f; }

    for (int t0 = 0; t0 < ct; t0 += 64) {
        __syncthreads();
        for (int c = tid; c < 512; c += 256) {
            int row = c >> 3, ch = (c & 7) * 8;
            st8s(&Kr_s[row][ch], *(const bf16x8*)&Krc [qb + (size_t)(t0 + row) * HD + ch]);
            st8s(&Ki_s[row][ch], *(const bf16x8*)&nKic[qb + (size_t)(t0 + row) * HD + ch]);
            st8s(&Vr_s[row][ch], *(const bf16x8*)&Vtc [qb + (size_t)row * NN + t0 + ch]);
            st8s(&Vi_s[row][ch], *(const bf16x8*)&Vtic[qb + (size_t)row * NN + t0 + ch]);
        }
        __syncthreads();

        // ---- scores ----
        f32x4 sacc[2][4];
#pragma unroll
        for (int nf = 0; nf < 4; nf++) {
            bf16x8 k0f = ld8s(&Kr_s[nf*16 + lr][lg*8]);
            bf16x8 k1f = ld8s(&Kr_s[nf*16 + lr][32 + lg*8]);
            bf16x8 i0f = ld8s(&Ki_s[nf*16 + lr][lg*8]);
            bf16x8 i1f = ld8s(&Ki_s[nf*16 + lr][32 + lg*8]);
#pragma unroll
            for (int mf = 0; mf < 2; mf++) {
                f32x4 a = (f32x4){0.f,0.f,0.f,0.f};
                a = MFMA(qr[mf][0], k0f, a);
                a = MFMA(qr[mf][1], k1f, a);
                a = MFMA(qi[mf][0], i0f, a);
                a = MFMA(qi[mf][1], i1f, a);
                sacc[mf][nf] = a;
            }
        }

        // tail masking (only in last tile)
        if (t0 + 64 > cnt) {
#pragma unroll
            for (int nf = 0; nf < 4; nf++) {
                if (t0 + nf*16 + lr >= cnt) {
#pragma unroll
                    for (int mf = 0; mf < 2; mf++)
#pragma unroll
                        for (int r = 0; r < 4; r++) sacc[mf][nf][r] = -1e9f;
                }
            }
        }

        // ---- online softmax (rows = lg*4+r, cols = nf*16+lr) ----
#pragma unroll
        for (int mf = 0; mf < 2; mf++) {
            float fac[4];
#pragma unroll
            for (int r = 0; r < 4; r++) {
                float v = fmaxf(fmaxf(sacc[mf][0][r], sacc[mf][1][r]),
                                fmaxf(sacc[mf][2][r], sacc[mf][3][r]));
                v = fmaxf(v, __shfl_xor(v, 1, 64));
                v = fmaxf(v, __shfl_xor(v, 2, 64));
                v = fmaxf(v, __shfl_xor(v, 4, 64));
                v = fmaxf(v, __shfl_xor(v, 8, 64));
                float mn = fmaxf(m_run[mf][r], v);
                fac[r] = __expf(m_run[mf][r] - mn);
                m_run[mf][r] = mn;
            }
            float psum[4] = {0.f, 0.f, 0.f, 0.f};
#pragma unroll
            for (int nf = 0; nf < 4; nf++)
#pragma unroll
                for (int r = 0; r < 4; r++) {
                    float p = __expf(sacc[mf][nf][r] - m_run[mf][r]);
                    psum[r] += p;
                    P_s[wave][mf*16 + lg*4 + r][nf*16 + lr] = (short)f2bf(p);
                }
#pragma unroll
            for (int r = 0; r < 4; r++) {
                float ps = psum[r];
                ps += __shfl_xor(ps, 1, 64);
                ps += __shfl_xor(ps, 2, 64);
                ps += __shfl_xor(ps, 4, 64);
                ps += __shfl_xor(ps, 8, 64);
                l_run[mf][r] = l_run[mf][r] * fac[r] + ps;
            }
#pragma unroll
            for (int nf = 0; nf < 4; nf++)
#pragma unroll
                for (int r = 0; r < 4; r++) {
                    o_r[mf][nf][r] *= fac[r];
                    o_i[mf][nf][r] *= fac[r];
                }
        }
        __syncthreads();   // P_s visibility

        // ---- PV ----
        bf16x8 pa[2][2];
#pragma unroll
        for (int mf = 0; mf < 2; mf++) {
            pa[mf][0] = ld8s(&P_s[wave][mf*16 + lr][lg*8]);
            pa[mf][1] = ld8s(&P_s[wave][mf*16 + lr][32 + lg*8]);
        }
#pragma unroll
        for (int nf = 0; nf < 4; nf++) {
            bf16x8 v0 = ld8s(&Vr_s[nf*16 + lr][lg*8]);
            bf16x8 v1 = ld8s(&Vr_s[nf*16 + lr][32 + lg*8]);
            bf16x8 w0 = ld8s(&Vi_s[nf*16 + lr][lg*8]);
            bf16x8 w1 = ld8s(&Vi_s[nf*16 + lr][32 + lg*8]);
#pragma unroll
            for (int mf = 0; mf < 2; mf++) {
                o_r[mf][nf] = MFMA(pa[mf][0], v0, o_r[mf][nf]);
                o_r[mf][nf] = MFMA(pa[mf][1], v1, o_r[mf][nf]);
                o_i[mf][nf] = MFMA(pa[mf][0], w0, o_i[mf][nf]);
                o_i[mf][nf] = MFMA(pa[mf][1], w1, o_i[mf][nf]);
            }
        }
    }

#pragma unroll
    for (int mf = 0; mf < 2; mf++) {
        float invl[4];
#pragma unroll
        for (int r = 0; r < 4; r++) invl[r] = 1.0f / l_run[mf][r];
#pragma unroll
        for (int nf = 0; nf < 4; nf++)
#pragma unroll
            for (int r = 0; r < 4; r++) {
                int row = n0 + mf*16 + lg*4 + r;
                int col = h*HD + nf*16 + lr;
                size_t o = ((size_t)(b*NN + row)) * DD + col;
                Aor[o] = f2bf(o_r[mf][nf][r] * invl[r]);
                Aoi[o] = f2bf(o_i[mf][nf][r] * invl[r]);
            }
    }
}

// ---------------------------------------------------------------------------
// Final complex GEMM + bias + residual, fp32 out stacked (2,B,N,D).
// grid (MM/128, DD/128), block 256.
// ---------------------------------------------------------------------------
__global__ __launch_bounds__(256) void final_mfma(
    const unsigned short* __restrict__ Ar, const unsigned short* __restrict__ Ai,
    const unsigned short* __restrict__ Wor, const unsigned short* __restrict__ Woi,
    const float* __restrict__ bor, const float* __restrict__ boi,
    const float* __restrict__ Zr, const float* __restrict__ Zi,
    float* __restrict__ out)
{
    __shared__ short Ar_s[128][40], Ai_s[128][40], Br_s[128][40], Bi_s[128][40];

    const int tid = threadIdx.x;
    const int lane = tid & 63, wave = tid >> 6;
    const int lr = lane & 15, lg = lane >> 4;
    const int wrow = (wave >> 1) * 64, wcol = (wave & 1) * 64;
    const int m0 = blockIdx.x * 128, o0 = blockIdx.y * 128;

    f32x4 accr[4][4], acci[4][4];
#pragma unroll
    for (int m = 0; m < 4; m++)
#pragma unroll
        for (int n = 0; n < 4; n++) {
            accr[m][n] = (f32x4){0.f,0.f,0.f,0.f};
            acci[m][n] = (f32x4){0.f,0.f,0.f,0.f};
        }

    for (int k0 = 0; k0 < DD; k0 += 32) {
        __syncthreads();
        for (int c = tid; c < 512; c += 256) {
            int row = c >> 2, ch = (c & 3) * 8;
            st8s(&Ar_s[row][ch], *(const bf16x8*)&Ar[(size_t)(m0 + row) * DD + k0 + ch]);
            st8s(&Ai_s[row][ch], *(const bf16x8*)&Ai[(size_t)(m0 + row) * DD + k0 + ch]);
            st8s(&Br_s[row][ch], *(const bf16x8*)&Wor[(size_t)(o0 + row) * DD + k0 + ch]);
            st8s(&Bi_s[row][ch], *(const bf16x8*)&Woi[(size_t)(o0 + row) * DD + k0 + ch]);
        }
        __syncthreads();

        bf16x8 ar[4], ai[4], nai[4], brf[4], bif[4];
#pragma unroll
        for (int m = 0; m < 4; m++) {
            ar[m]  = ld8s(&Ar_s[wrow + m*16 + lr][lg*8]);
            ai[m]  = ld8s(&Ai_s[wrow + m*16 + lr][lg*8]);
            nai[m] = ai[m] ^ (short)0x8000;
        }
#pragma unroll
        for (int n = 0; n < 4; n++) {
            brf[n] = ld8s(&Br_s[wcol + n*16 + lr][lg*8]);
            bif[n] = ld8s(&Bi_s[wcol + n*16 + lr][lg*8]);
        }
#pragma unroll
        for (int m = 0; m < 4; m++)
#pragma unroll
            for (int n = 0; n < 4; n++) {
                accr[m][n] = MFMA(ar[m],  brf[n], accr[m][n]);
                accr[m][n] = MFMA(nai[m], bif[n], accr[m][n]);
                acci[m][n] = MFMA(ar[m],  bif[n], acci[m][n]);
                acci[m][n] = MFMA(ai[m],  brf[n], acci[m][n]);
            }
    }

#pragma unroll
    for (int mi = 0; mi < 4; mi++)
#pragma unroll
        for (int nj = 0; nj < 4; nj++) {
            const int o = o0 + wcol + nj*16 + lr;
            const float brv = bor[o], biv = boi[o];
#pragma unroll
            for (int reg = 0; reg < 4; reg++) {
                const int m = m0 + wrow + mi*16 + lg*4 + reg;
                size_t zi = (size_t)m * DD + o;
                out[zi] = accr[mi][nj][reg] + brv + Zr[zi];
                out[(size_t)MM * DD + zi] = acci[mi][nj][reg] + biv + Zi[zi];
            }
        }
}

// ---------------------------------------------------------------------------
extern "C" void kernel_launch(void* const* d_in, const int* in_sizes, int n_in,
                              void* d_out, int out_size, void* d_ws, size_t ws_size,
                              hipStream_t stream)
{
    const float* Zr  = (const float*)d_in[0];
    const float* Zi  = (const float*)d_in[1];
    const float* wqr = (const float*)d_in[2];
    const float* wqi = (const float*)d_in[3];
    const float* bqr = (const float*)d_in[4];
    const float* bqi = (const float*)d_in[5];
    const float* wkr = (const float*)d_in[6];
    const float* wki = (const float*)d_in[7];
    const float* bkr = (const float*)d_in[8];
    const float* bki = (const float*)d_in[9];
    const float* wvr = (const float*)d_in[10];
    const float* wvi = (const float*)d_in[11];
    const float* bvr = (const float*)d_in[12];
    const float* bvi = (const float*)d_in[13];
    const float* wor = (const float*)d_in[14];
    const float* woi = (const float*)d_in[15];
    const float* bor = (const float*)d_in[16];
    const float* boi = (const float*)d_in[17];
    const int*  mask = (const int*)d_in[18];

    unsigned short* w16 = (unsigned short*)d_ws;
    const size_t ZN = (size_t)MM * DD;   // 4,194,304
    const size_t WN = (size_t)DD * DD;   // 1,048,576
    unsigned short* Zr16  = w16;              unsigned short* Zi16  = Zr16 + ZN;
    unsigned short* Wqr16 = Zi16 + ZN;        unsigned short* Wqi16 = Wqr16 + WN;
    unsigned short* Wkr16 = Wqi16 + WN;       unsigned short* Wki16 = Wkr16 + WN;
    unsigned short* Wvr16 = Wki16 + WN;       unsigned short* Wvi16 = Wvr16 + WN;
    unsigned short* Wor16 = Wvi16 + WN;       unsigned short* Woi16 = Wor16 + WN;
    unsigned short* Qr16  = Woi16 + WN;       unsigned short* Qi16  = Qr16 + ZN;
    unsigned short* Krc16 = Qi16 + ZN;        unsigned short* nKic16 = Krc16 + ZN;
    unsigned short* Vtr16 = nKic16 + ZN;      unsigned short* Vti16 = Vtr16 + ZN;
    unsigned short* Aor16 = Vti16 + ZN;       unsigned short* Aoi16 = Aor16 + ZN;
    int* idxArr = (int*)(Aoi16 + ZN);
    int* cntArr = idxArr + BB * NN;

    mask_scan<<<BB, 256, 0, stream>>>(mask, idxArr, cntArr);

    cvt_fused<<<8192, 256, 0, stream>>>(
        Zr, Zi, wqr, wqi, wkr, wki, wvr, wvi, wor, woi,
        Zr16, Zi16, Wqr16, Wqi16, Wkr16, Wki16, Wvr16, Wvi16, Wor16, Woi16);

    proj_q<<<dim3(MM/128, DD/128), 256, 0, stream>>>(
        Zr16, Zi16, Wqr16, Wqi16, bqr, bqi, Qr16, Qi16);

    proj_kv<<<dim3(NN/128, DD/128, BB*2), 256, 0, stream>>>(
        Zr16, Zi16, Wkr16, Wki16, Wvr16, Wvi16,
        bkr, bki, bvr, bvi, idxArr, cntArr,
        Krc16, nKic16, Vtr16, Vti16);

    attn_mfma<<<dim3(NN/128, HH, BB), 256, 0, stream>>>(
        Qr16, Qi16, Krc16, nKic16, Vtr16, Vti16, cntArr, Aor16, Aoi16);

    final_mfma<<<dim3(MM/128, DD/128), 256, 0, stream>>>(
        Aor16, Aoi16, Wor16, Woi16, bor, boi, Zr, Zi, (float*)d_out);
}